// Round 2
// baseline (1579.378 us; speedup 1.0000x reference)
//
#include <hip/hip_runtime.h>
#include <hip/hip_bf16.h>
#include <math.h>

using bf16 = __hip_bfloat16;
typedef __attribute__((ext_vector_type(8))) short bf16x8;
typedef __attribute__((ext_vector_type(4))) float f32x4;

#define DEVI __device__ __forceinline__

DEVI float b2f(bf16 v) { return __bfloat162float(v); }
DEVI bf16 f2b(float v) { return __float2bfloat16(v); }
DEVI float geluf(float x) { return 0.5f * x * (1.0f + erff(x * 0.70710678118654752f)); }
DEVI float siluf(float x) { return x / (1.0f + expf(-x)); }

// ---------------- prep kernels ----------------
__global__ __launch_bounds__(256) void cast_kernel(const float* __restrict__ in,
                                                   bf16* __restrict__ out, int n4) {
  int i = blockIdx.x * 256 + threadIdx.x;
  if (i >= n4) return;
  float4 v = reinterpret_cast<const float4*>(in)[i];
  bf16 o[4] = { f2b(v.x), f2b(v.y), f2b(v.z), f2b(v.w) };
  reinterpret_cast<uint2*>(out)[i] = *reinterpret_cast<uint2*>(o);
}

__global__ __launch_bounds__(256) void pmean_kernel(const float* __restrict__ rel,
                                                    float* __restrict__ pm) {
  int h = blockIdx.x * 256 + threadIdx.x;  // 1024 total
  float s = 0.f;
  for (int m = 0; m < 1024; ++m) s += rel[m * 1024 + h];
  pm[h] = s * (1.0f / 1024.0f);
}

__global__ __launch_bounds__(64) void wb2sum_kernel(const float* __restrict__ wb,
                                                    float* __restrict__ out) {
  int e = blockIdx.x;  // 2048 blocks, 1 wave each
  float s = 0.f;
  for (int j = threadIdx.x; j < 1024; j += 64) s += wb[(long)e * 2048 + 1024 + j];
#pragma unroll
  for (int off = 32; off > 0; off >>= 1) s += __shfl_down(s, off);
  if (threadIdx.x == 0) out[e] = s;
}

// ---------------- LayerNorm kernels ----------------
template<bool POS>
__global__ __launch_bounds__(256) void ln1024_kernel(
    const float* __restrict__ x, const float* __restrict__ w, const float* __restrict__ b,
    bf16* __restrict__ out, const float* __restrict__ pmean, float* __restrict__ pos) {
  __shared__ float red[12];
  long row = blockIdx.x;
  int t = threadIdx.x, lane = t & 63, wid = t >> 6;
  float4 xv = reinterpret_cast<const float4*>(x + row * 1024)[t];
  float s = xv.x + xv.y + xv.z + xv.w;
  float ss = xv.x * xv.x + xv.y * xv.y + xv.z * xv.z + xv.w * xv.w;
#pragma unroll
  for (int off = 32; off > 0; off >>= 1) { s += __shfl_down(s, off); ss += __shfl_down(ss, off); }
  if (lane == 0) { red[wid] = s; red[4 + wid] = ss; }
  __syncthreads();
  s = red[0] + red[1] + red[2] + red[3];
  ss = red[4] + red[5] + red[6] + red[7];
  float mean = s * (1.0f / 1024.0f);
  float rstd = rsqrtf(ss * (1.0f / 1024.0f) - mean * mean + 1e-5f);
  float4 wv = reinterpret_cast<const float4*>(w)[t];
  float4 bv = reinterpret_cast<const float4*>(b)[t];
  float h0 = (xv.x - mean) * rstd * wv.x + bv.x;
  float h1 = (xv.y - mean) * rstd * wv.y + bv.y;
  float h2 = (xv.z - mean) * rstd * wv.z + bv.z;
  float h3 = (xv.w - mean) * rstd * wv.w + bv.w;
  bf16 o[4] = { f2b(h0), f2b(h1), f2b(h2), f2b(h3) };
  reinterpret_cast<uint2*>(out + row * 1024)[t] = *reinterpret_cast<uint2*>(o);
  if (POS) {
    float4 pv = reinterpret_cast<const float4*>(pmean)[t];
    float d = h0 * pv.x + h1 * pv.y + h2 * pv.z + h3 * pv.w;
#pragma unroll
    for (int off = 32; off > 0; off >>= 1) d += __shfl_down(d, off);
    if (lane == 0) red[8 + wid] = d;
    __syncthreads();
    if (t == 0) pos[row] = red[8] + red[9] + red[10] + red[11];
  }
}

__global__ __launch_bounds__(256) void ln2048_bf16_kernel(
    const bf16* __restrict__ in, const float* __restrict__ w, const float* __restrict__ b,
    bf16* __restrict__ out) {
  __shared__ float red[8];
  long row = blockIdx.x;
  int t = threadIdx.x, lane = t & 63, wid = t >> 6;
  bf16 tv[8];
  *reinterpret_cast<int4*>(tv) = reinterpret_cast<const int4*>(in + row * 2048)[t];
  float v[8], s = 0.f, ss = 0.f;
#pragma unroll
  for (int j = 0; j < 8; ++j) { v[j] = b2f(tv[j]); s += v[j]; ss += v[j] * v[j]; }
#pragma unroll
  for (int off = 32; off > 0; off >>= 1) { s += __shfl_down(s, off); ss += __shfl_down(ss, off); }
  if (lane == 0) { red[wid] = s; red[4 + wid] = ss; }
  __syncthreads();
  s = red[0] + red[1] + red[2] + red[3];
  ss = red[4] + red[5] + red[6] + red[7];
  float mean = s * (1.0f / 2048.0f);
  float rstd = rsqrtf(ss * (1.0f / 2048.0f) - mean * mean + 1e-5f);
  int base = t * 8;
  bf16 o[8];
#pragma unroll
  for (int j = 0; j < 8; ++j) o[j] = f2b((v[j] - mean) * rstd * w[base + j] + b[base + j]);
  reinterpret_cast<int4*>(out + row * 2048)[t] = *reinterpret_cast<int4*>(o);
}

// ---------------- activation + cross-norm (in-place on q,k,v) ----------------
__global__ __launch_bounds__(256) void act_norm_kernel(
    bf16* __restrict__ qp, bf16* __restrict__ kp, bf16* __restrict__ vp) {
  __shared__ float red[8];
  long row = blockIdx.x;
  int t = threadIdx.x, lane = t & 63, wid = t >> 6;
  long ob = row * 2048 + t * 8;
  bf16 tq[8], tk[8], tv[8];
  *reinterpret_cast<int4*>(tq) = *reinterpret_cast<const int4*>(qp + ob);
  *reinterpret_cast<int4*>(tk) = *reinterpret_cast<const int4*>(kp + ob);
  *reinterpret_cast<int4*>(tv) = *reinterpret_cast<const int4*>(vp + ob);
  float qs[8], ks[8];
  float sq = 0.f, sk = 0.f;
#pragma unroll
  for (int j = 0; j < 8; ++j) {
    float q = b2f(tq[j]); qs[j] = siluf(q); sq += qs[j] * qs[j];
    float k = b2f(tk[j]); ks[j] = siluf(k); sk += ks[j] * ks[j];
  }
#pragma unroll
  for (int off = 32; off > 0; off >>= 1) { sq += __shfl_down(sq, off); sk += __shfl_down(sk, off); }
  if (lane == 0) { red[wid] = sq; red[4 + wid] = sk; }
  __syncthreads();
  sq = red[0] + red[1] + red[2] + red[3];
  sk = red[4] + red[5] + red[6] + red[7];
  float rq = 1.0f / fmaxf(sqrtf(sq), 1e-12f);
  float rk = 1.0f / fmaxf(sqrtf(sk), 1e-12f);
  bf16 oq[8], ok[8], ov[8];
#pragma unroll
  for (int j = 0; j < 8; ++j) {
    float qn = qs[j] * rq + 0.1f * ks[j];
    float kn = ks[j] * rk + 0.1f * qn;
    oq[j] = f2b(qn); ok[j] = f2b(kn);
    ov[j] = f2b(geluf(b2f(tv[j])));
  }
  *reinterpret_cast<int4*>(qp + ob) = *reinterpret_cast<int4*>(oq);
  *reinterpret_cast<int4*>(kp + ob) = *reinterpret_cast<int4*>(ok);
  *reinterpret_cast<int4*>(vp + ob) = *reinterpret_cast<int4*>(ov);
}

// ---------------- depthwise conv (kernel 3, pad 1) over L ----------------
__global__ __launch_bounds__(256) void dwconv_kernel(
    const bf16* __restrict__ in, bf16* __restrict__ out, const float* __restrict__ cw) {
  long gid = (long)blockIdx.x * 256 + threadIdx.x;  // 2,097,152 vecs of 8
  int e0 = (int)(gid & 255) * 8;
  int l = (int)((gid >> 8) & 1023);
  long bl = gid >> 8;
  const bf16* mid = in + (bl * 2048 + e0);
  bf16 tm[8], tp[8], tn[8];
  *reinterpret_cast<int4*>(tm) = *reinterpret_cast<const int4*>(mid);
  if (l > 0)    *reinterpret_cast<int4*>(tp) = *reinterpret_cast<const int4*>(mid - 2048);
  if (l < 1023) *reinterpret_cast<int4*>(tn) = *reinterpret_cast<const int4*>(mid + 2048);
  bf16 o[8];
#pragma unroll
  for (int j = 0; j < 8; ++j) {
    const float* wp = cw + (e0 + j) * 3;
    float a = wp[1] * b2f(tm[j]);
    if (l > 0) a += wp[0] * b2f(tp[j]);
    if (l < 1023) a += wp[2] * b2f(tn[j]);
    o[j] = f2b(a);
  }
  *reinterpret_cast<int4*>(out + (bl * 2048 + e0)) = *reinterpret_cast<int4*>(o);
}

// ---------------- GEMM: C[m,n] = sum_k A*B with templated epilogue ----------------
// NT: A (M,K) row-major, B (N,K) row-major.  TN: A (K,M), B (K,N) row-major.
enum { EPI_QKV = 0, EPI_BETA = 1, EPI_BF16 = 2, EPI_SCALE = 3, EPI_RES_F32 = 4, EPI_GELU = 5 };

template<int EPI, bool TN>
__global__ __launch_bounds__(256) void gemm_kernel(
    const bf16* __restrict__ A, int lda, long sA,
    const bf16* __restrict__ B, int ldb, long sB,
    void* __restrict__ Cv, int ldc, long sC, int K,
    const float* __restrict__ bias, const float* __restrict__ aux_row,
    const float* __restrict__ aux_col, const bf16* __restrict__ vconv,
    const float* __restrict__ resid, const float* __restrict__ scale_ptr,
    bf16* __restrict__ p2, bf16* __restrict__ p3) {
  __shared__ bf16 As[128][72];
  __shared__ bf16 Bs[128][72];
  const int bz = blockIdx.z;
  A += (long)bz * sA;
  B += (long)bz * sB;
  const int m0 = blockIdx.y * 128, n0 = blockIdx.x * 128;
  const int t = threadIdx.x;
  const int lane = t & 63, wid = t >> 6;
  const int wm = (wid >> 1) * 64, wn = (wid & 1) * 64;
  const int r16 = lane & 15, kg = (lane >> 4) * 8;
  f32x4 acc[4][4] = {};
  for (int k0 = 0; k0 < K; k0 += 64) {
    if (!TN) {
#pragma unroll
      for (int p = 0; p < 4; ++p) {
        int vid = p * 256 + t;
        int r = vid >> 3, c = (vid & 7) * 8;
        *reinterpret_cast<int4*>(&As[r][c]) =
            *reinterpret_cast<const int4*>(&A[(long)(m0 + r) * lda + k0 + c]);
        *reinterpret_cast<int4*>(&Bs[r][c]) =
            *reinterpret_cast<const int4*>(&B[(long)(n0 + r) * ldb + k0 + c]);
      }
    } else {
#pragma unroll
      for (int p = 0; p < 4; ++p) {
        int vid = p * 256 + t;
        int kr = vid >> 4, c = (vid & 15) * 8;
        bf16 tA[8], tB[8];
        *reinterpret_cast<int4*>(tA) =
            *reinterpret_cast<const int4*>(&A[(long)(k0 + kr) * lda + m0 + c]);
        *reinterpret_cast<int4*>(tB) =
            *reinterpret_cast<const int4*>(&B[(long)(k0 + kr) * ldb + n0 + c]);
#pragma unroll
        for (int j = 0; j < 8; ++j) { As[c + j][kr] = tA[j]; Bs[c + j][kr] = tB[j]; }
      }
    }
    __syncthreads();
#pragma unroll
    for (int kk = 0; kk < 64; kk += 32) {
      bf16x8 af[4], bfr[4];
#pragma unroll
      for (int i = 0; i < 4; ++i)
        af[i] = *reinterpret_cast<const bf16x8*>(&As[wm + i * 16 + r16][kk + kg]);
#pragma unroll
      for (int j = 0; j < 4; ++j)
        bfr[j] = *reinterpret_cast<const bf16x8*>(&Bs[wn + j * 16 + r16][kk + kg]);
#pragma unroll
      for (int i = 0; i < 4; ++i)
#pragma unroll
        for (int j = 0; j < 4; ++j)
          acc[i][j] = __builtin_amdgcn_mfma_f32_16x16x32_bf16(af[i], bfr[j], acc[i][j], 0, 0, 0);
    }
    __syncthreads();
  }
  float scl = 1.0f;
  if (EPI == EPI_SCALE) scl = scale_ptr[0];
  const int rb = (lane >> 4) * 4;
#pragma unroll
  for (int i = 0; i < 4; ++i) {
#pragma unroll
    for (int j = 0; j < 4; ++j) {
#pragma unroll
      for (int r = 0; r < 4; ++r) {
        const long gm = m0 + wm + i * 16 + rb + r;
        const int gn = n0 + wn + j * 16 + r16;
        const long idx = (long)bz * sC + gm * (long)ldc + gn;
        float v = acc[i][j][r];
        if (EPI == EPI_QKV) {
          const int seg = gn >> 11, cc = gn & 2047;
          bf16* dst = (seg == 0) ? (bf16*)Cv : (seg == 1) ? p2 : p3;
          dst[gm * 2048 + cc] = f2b(v + bias[gn]);
        } else if (EPI == EPI_BETA) {
          float tt = v + bias[gn] + aux_row[gm] * aux_col[gn];
          float be = 0.9f / (1.0f + expf(-tt)) + 0.1f;
          ((bf16*)Cv)[idx] = f2b(be * b2f(vconv[idx]));
        } else if (EPI == EPI_BF16) {
          ((bf16*)Cv)[idx] = f2b(v);
        } else if (EPI == EPI_SCALE) {
          ((bf16*)Cv)[idx] = f2b(v * scl);
        } else if (EPI == EPI_RES_F32) {
          ((float*)Cv)[idx] = v + bias[gn] + resid[idx];
        } else {  // EPI_GELU
          ((bf16*)Cv)[idx] = f2b(geluf(v + bias[gn]));
        }
      }
    }
  }
}

// ---------------- orchestration ----------------
extern "C" void kernel_launch(void* const* d_in, const int* in_sizes, int n_in,
                              void* d_out, int out_size, void* d_ws, size_t ws_size,
                              hipStream_t stream) {
  (void)in_sizes; (void)n_in; (void)out_size;
  const float* x       = (const float*)d_in[0];
  const float* ln1_w   = (const float*)d_in[1];
  const float* ln1_b   = (const float*)d_in[2];
  const float* ln2_w   = (const float*)d_in[3];
  const float* ln2_b   = (const float*)d_in[4];
  const float* w_qkv   = (const float*)d_in[5];
  const float* b_qkv   = (const float*)d_in[6];
  const float* w_out   = (const float*)d_in[7];
  const float* b_out   = (const float*)d_in[8];
  const float* rel_pos = (const float*)d_in[9];
  const float* w_beta  = (const float*)d_in[10];
  const float* b_beta  = (const float*)d_in[11];
  const float* w1      = (const float*)d_in[12];
  const float* b1      = (const float*)d_in[13];
  const float* w2      = (const float*)d_in[14];
  const float* b2      = (const float*)d_in[15];
  const float* conv_w  = (const float*)d_in[16];
  const float* attn_sc = (const float*)d_in[17];
  float* out = (float*)d_out;

  // ---- workspace layout: 180,400,128 bytes total ----
  if (ws_size < 180400128UL) return;  // diagnostic guard: clean absmax-fail instead of fault
  char* ws = (char*)d_ws;
  bf16*  wbuf    = (bf16*)(ws + 0);            // 12,582,912 B (largest weight: w_qkv)
  float* pmean   = (float*)(ws + 12582912UL);  // 4 KB
  float* wb2s    = (float*)(ws + 12587008UL);  // 8 KB
  float* posinfo = (float*)(ws + 12595200UL);  // 32 KB
  bf16*  bufH    = (bf16*)(ws + 12627968UL);   // 16 MiB  : h / h2
  bf16*  bufQ    = (bf16*)(ws + 29405184UL);   // 32 MiB  : q_pre -> k_conv -> attn -> m1(lo)
  bf16*  bufK    = (bf16*)(ws + 62959616UL);   // 32 MiB  : k_pre -> v_conv -> out_ln -> m1(hi)
  bf16*  bufV    = (bf16*)(ws + 96514048UL);   // 32 MiB  : v_pre -> v_new -> x2(f32)
  bf16*  bufD    = (bf16*)(ws + 130068480UL);  // 32 MiB  : q_conv
  bf16*  bufS    = (bf16*)(ws + 163622912UL);  // 16 MiB  : state (2 batches/chunk)
  float* x2      = (float*)bufV;

  // prep reductions
  pmean_kernel<<<4, 256, 0, stream>>>(rel_pos, pmean);
  wb2sum_kernel<<<2048, 64, 0, stream>>>(w_beta, wb2s);

  // LN1 + pos_info
  ln1024_kernel<true><<<8192, 256, 0, stream>>>(x, ln1_w, ln1_b, bufH, pmean, posinfo);

  // qkv = h @ w_qkv.T + b_qkv, split into q/k/v buffers
  cast_kernel<<<6144, 256, 0, stream>>>(w_qkv, wbuf, 1572864);
  gemm_kernel<EPI_QKV, false><<<dim3(48, 64, 1), 256, 0, stream>>>(
      bufH, 1024, 0, wbuf, 1024, 0, bufQ, 2048, 0, 1024,
      b_qkv, nullptr, nullptr, nullptr, nullptr, nullptr, bufK, bufV);

  // silu/silu/gelu + cross-normalize (in place)
  act_norm_kernel<<<8192, 256, 0, stream>>>(bufQ, bufK, bufV);

  // depthwise conv: q: Q->D, k: K->Q, v: V->K
  dwconv_kernel<<<8192, 256, 0, stream>>>(bufQ, bufD, conv_w);
  dwconv_kernel<<<8192, 256, 0, stream>>>(bufK, bufQ, conv_w);
  dwconv_kernel<<<8192, 256, 0, stream>>>(bufV, bufK, conv_w);

  // beta = sigmoid(h@Wb[:, :H].T + pos*wb2sum + b)*0.9+0.1 ; v_new = beta * v_conv -> bufV
  cast_kernel<<<4096, 256, 0, stream>>>(w_beta, wbuf, 1048576);
  gemm_kernel<EPI_BETA, false><<<dim3(16, 64, 1), 256, 0, stream>>>(
      bufH, 1024, 0, wbuf, 2048, 0, bufV, 2048, 0, 1024,
      b_beta, posinfo, wb2s, bufK, nullptr, nullptr, nullptr, nullptr);

  // attention: per 2-batch chunk: state[f,e] = sum_l v_new[l,f] k[l,e]; out = q @ state^T
  for (int c = 0; c < 4; ++c) {
    const long co = (long)c * 4194304;
    gemm_kernel<EPI_BF16, true><<<dim3(16, 16, 2), 256, 0, stream>>>(
        bufV + co, 2048, 2097152, bufQ + co, 2048, 2097152, bufS, 2048, 4194304, 1024,
        nullptr, nullptr, nullptr, nullptr, nullptr, nullptr, nullptr, nullptr);
    gemm_kernel<EPI_SCALE, false><<<dim3(16, 8, 2), 256, 0, stream>>>(
        bufD + co, 2048, 2097152, bufS, 2048, 4194304, bufQ + co, 2048, 2097152, 2048,
        nullptr, nullptr, nullptr, nullptr, nullptr, attn_sc, nullptr, nullptr);
  }

  // LN2: attn(bufQ) -> out_ln(bufK)
  ln2048_bf16_kernel<<<8192, 256, 0, stream>>>(bufQ, ln2_w, ln2_b, bufK);

  // x2 = x + out_ln @ w_out.T + b_out   (f32, into bufV)
  cast_kernel<<<2048, 256, 0, stream>>>(w_out, wbuf, 524288);
  gemm_kernel<EPI_RES_F32, false><<<dim3(8, 64, 1), 256, 0, stream>>>(
      bufK, 2048, 0, wbuf, 2048, 0, x2, 1024, 0, 2048,
      b_out, nullptr, nullptr, nullptr, x, nullptr, nullptr, nullptr);

  // h2 = LN(x2) -> bufH
  ln1024_kernel<false><<<8192, 256, 0, stream>>>(x2, ln1_w, ln1_b, bufH, nullptr, nullptr);

  // m1 = gelu(h2 @ w1.T + b1)  -> spans bufQ..bufK (64 MiB)
  cast_kernel<<<4096, 256, 0, stream>>>(w1, wbuf, 1048576);
  gemm_kernel<EPI_GELU, false><<<dim3(32, 64, 1), 256, 0, stream>>>(
      bufH, 1024, 0, wbuf, 1024, 0, bufQ, 4096, 0, 1024,
      b1, nullptr, nullptr, nullptr, nullptr, nullptr, nullptr, nullptr);

  // out = x2 + m1 @ w2.T + b2
  cast_kernel<<<4096, 256, 0, stream>>>(w2, wbuf, 1048576);
  gemm_kernel<EPI_RES_F32, false><<<dim3(8, 64, 1), 256, 0, stream>>>(
      bufQ, 4096, 0, wbuf, 4096, 0, out, 1024, 0, 4096,
      b2, nullptr, nullptr, nullptr, x2, nullptr, nullptr, nullptr);
}